// Round 6
// baseline (127.023 us; speedup 1.0000x reference)
//
#include <hip/hip_runtime.h>

#define BATCH 32768
#define DIM   256
#define NEXP  8
#define MT    32          // rows per tile
#define STRIDE 264        // DIM + 8 bf16 pad (measured 0 bank conflicts)

typedef __bf16 bf16x8 __attribute__((ext_vector_type(8)));
typedef __bf16 bf16x4 __attribute__((ext_vector_type(4)));
typedef float  f32x16 __attribute__((ext_vector_type(16)));

static __device__ __forceinline__ float sigmoid_f(float x) {
    return __builtin_amdgcn_rcpf(1.f + __expf(-x));
}
static __device__ __forceinline__ float tanh_f(float x) {
    return 1.f - 2.f * __builtin_amdgcn_rcpf(__expf(2.f * x) + 1.f);
}

// LDS-only barrier: waits own LDS ops (lgkmcnt) then s_barrier, WITHOUT the
// vmcnt(0) drain __syncthreads() emits. Valid here because all cross-thread
// data flows through LDS (ab/rows); global loads are consumed by the issuing
// thread and `out` is never read back. Keeps next-tile gather loads and
// epilogue store-acks in flight across barriers (the R5 residual stall).
static __device__ __forceinline__ void lds_barrier() {
    asm volatile("s_waitcnt lgkmcnt(0)\n\ts_barrier" ::: "memory");
}

// ---- fused prep (unchanged).
// Blocks 0..255: pack W1/W2 fp32->bf16 into MFMA-B-fragment order.
// Layout (bf16x8 units): dst = [e][nt][ks][kh*32+nl], value j = W[e][nt*32+nl][ks*16+kh*8+j]
// Blocks 256..383: scatter sample indices into per-expert regions.
__global__ void prep_kernel(const float* __restrict__ W1, const float* __restrict__ W2,
                            const float* __restrict__ t,
                            bf16x8* __restrict__ W1p, bf16x8* __restrict__ W2p,
                            int* __restrict__ cursor, int* __restrict__ idxb) {
    const int b = blockIdx.x;
    if (b < 256) {
        const int tid = b * 256 + threadIdx.x;   // = e*8192 + col*32 + ks*2 + kh
        const int kh  = tid & 1;
        const int ks  = (tid >> 1) & 15;
        const int col = (tid >> 5) & 255;
        const int e   = tid >> 13;
        const long src = (long)tid * 8;          // consecutive floats -> coalesced
        const float4 a0 = *(const float4*)(W1 + src);
        const float4 a1 = *(const float4*)(W1 + src + 4);
        const float4 c0 = *(const float4*)(W2 + src);
        const float4 c1 = *(const float4*)(W2 + src + 4);
        bf16x8 w1, w2;
        w1[0] = (__bf16)a0.x; w1[1] = (__bf16)a0.y; w1[2] = (__bf16)a0.z; w1[3] = (__bf16)a0.w;
        w1[4] = (__bf16)a1.x; w1[5] = (__bf16)a1.y; w1[6] = (__bf16)a1.z; w1[7] = (__bf16)a1.w;
        w2[0] = (__bf16)c0.x; w2[1] = (__bf16)c0.y; w2[2] = (__bf16)c0.z; w2[3] = (__bf16)c0.w;
        w2[4] = (__bf16)c1.x; w2[5] = (__bf16)c1.y; w2[6] = (__bf16)c1.z; w2[7] = (__bf16)c1.w;
        const int dst = (e << 13) | ((col >> 5) << 10) | (ks << 6) | (kh << 5) | (col & 31);
        W1p[dst] = w1;
        W2p[dst] = w2;
    } else {
        __shared__ int h[NEXP], base[NEXP];
        if (threadIdx.x < NEXP) h[threadIdx.x] = 0;
        __syncthreads();
        const int i = (b - 256) * 256 + threadIdx.x;
        const int e = min((int)(t[i] * 8.0f), NEXP - 1);
        const int lr = atomicAdd(&h[e], 1);
        __syncthreads();
        if (threadIdx.x < NEXP)
            base[threadIdx.x] = atomicAdd(&cursor[threadIdx.x], h[threadIdx.x]);
        __syncthreads();
        idxb[e * BATCH + base[e] + lr] = i;
    }
}

// ---- grouped fused 2-layer MLP, expert-pinned blocks, weights in registers,
// LDS-only barriers. 256 blocks (1/CU) x 512 threads (8 waves x 32 cols).
// Block b owns expert b>>5, tiles (b&31)+32k (~4 each). Both GEMMs' B-frags
// in 128 VGPRs (loaded once). Inner loops pure ds_read_b128+MFMA. Next
// tile's y rows prefetch into regs and now genuinely stay in flight across
// barriers (lds_barrier has no vmcnt drain — R5's hidden serializer).
__global__ void __launch_bounds__(512, 2)
mlp_kernel(const float* __restrict__ y,
           const float* __restrict__ scales,
           const float* __restrict__ shifta,
           const float* __restrict__ shiftb,
           const float* __restrict__ b1,
           const float* __restrict__ b2,
           const bf16x8* __restrict__ W1p,
           const bf16x8* __restrict__ W2p,
           const int* __restrict__ cnt,
           const int* __restrict__ idxb,
           float* __restrict__ out) {
    __shared__ __bf16 ab[MT * STRIDE];   // y tile (bf16), then tanh(h); 16.9 KB
    __shared__ int rows[MT];

    const int tx   = threadIdx.x;
    const int wave = tx >> 6;     // 0..7
    const int lane = tx & 63;
    const int nl   = lane & 31;
    const int kh   = lane >> 5;
    const int n    = wave * 32 + nl;   // this thread's output column (fixed)

    const int e    = blockIdx.x >> 5;   // expert pinned to block
    const int slot = blockIdx.x & 31;   // which tile-stripe of this expert
    const int ce   = cnt[e];
    const int nt_e = (ce + MT - 1) >> 5;
    if (slot >= nt_e) return;           // uniform per block
    const int* idx_e = idxb + e * BATCH;

    // ---- load both GEMMs' B-fragments into registers (once per block)
    const bf16x8* w1p = W1p + (e << 13) + (wave << 10) + lane;
    const bf16x8* w2p = W2p + (e << 13) + (wave << 10) + lane;
    bf16x8 wA[16], wB[16];
#pragma unroll
    for (int ks = 0; ks < 16; ++ks) {
        wA[ks] = w1p[ks << 6];
        wB[ks] = w2p[ks << 6];
    }

    // ---- hoisted per-thread epilogue constants (e and n fixed)
    const float sa = sigmoid_f(shifta[0]);
    const float sb = sigmoid_f(shiftb[0]);
    const float k1 = 0.5f * (sb + sa);           // 0.5*(b-a), a=-sa, b=sb
    const float k2 = 0.5f * (sb - sa);           // 0.5*(a+b)
    const bool needy = (k2 != 0.0f);             // with given inputs k2==0 exactly
    const float c1  = k1 * sigmoid_f(scales[n]);
    const float b1v = b1[(e << 8) | n];
    const float b2v = b2[(e << 8) | n];

    // ---- prologue: stage first tile
    int ti = slot;
    int nrows = min(MT, ce - ti * MT);
    {
        const int rbase = ti * MT;
#pragma unroll
        for (int p = 0; p < 4; ++p) {
            const int r  = p * 8 + wave;
            const int rr = min(r, nrows - 1);
            const int g  = idx_e[rbase + rr];
            if (lane == 0) rows[r] = (r < nrows) ? g : -1;
            const float4 v = *(const float4*)(y + (long)g * DIM + lane * 4);
            bf16x4 w;
            w[0] = (__bf16)v.x; w[1] = (__bf16)v.y; w[2] = (__bf16)v.z; w[3] = (__bf16)v.w;
            *(bf16x4*)(ab + r * STRIDE + lane * 4) = w;
        }
    }
    lds_barrier();

    for (;;) {
        // ---- issue next tile's gather into regs (stays in flight across
        // the lgkm-only barriers; consumed at the late stage-write)
        const int ti2 = ti + 32;
        const bool have_next = (ti2 < nt_e);
        int nrows2 = 0;
        int g2v[4];
        float4 v2[4];
        if (have_next) {
            nrows2 = min(MT, ce - ti2 * MT);
            const int rbase2 = ti2 * MT;
#pragma unroll
            for (int p = 0; p < 4; ++p) {
                const int r  = p * 8 + wave;
                const int rr = min(r, nrows2 - 1);
                g2v[p] = idx_e[rbase2 + rr];
            }
#pragma unroll
            for (int p = 0; p < 4; ++p)
                v2[p] = *(const float4*)(y + (long)g2v[p] * DIM + lane * 4);
        }

        const __bf16* apt0 = ab + nl * STRIDE + kh * 8;   // A-frag base, rows 0..31

        // ---- GEMM1: h = y @ W1[e]^T   (pure LDS + reg-resident B)
        f32x16 acc = {};
#pragma unroll
        for (int ks = 0; ks < 16; ++ks) {
            bf16x8 a0 = *(const bf16x8*)(apt0 + ks * 16);
            acc = __builtin_amdgcn_mfma_f32_32x32x16_bf16(a0, wA[ks], acc, 0, 0, 0);
        }
        lds_barrier();     // GEMM1 ds-reads done; does NOT drain prefetch vmcnt

        // ---- tanh(h + b1) -> ab (C/D: col=nl, row=(r&3)+8*(r>>2)+4*kh)
#pragma unroll
        for (int r = 0; r < 16; ++r) {
            const int row = (r & 3) + ((r >> 2) << 3) + (kh << 2);
            ab[row * STRIDE + n] = (__bf16)tanh_f(acc[r] + b1v);
        }
        lds_barrier();

        // ---- GEMM2: f = h @ W2[e]^T
        f32x16 acc2 = {};
#pragma unroll
        for (int ks = 0; ks < 16; ++ks) {
            bf16x8 a0 = *(const bf16x8*)(apt0 + ks * 16);
            acc2 = __builtin_amdgcn_mfma_f32_32x32x16_bf16(a0, wB[ks], acc2, 0, 0, 0);
        }

        // ---- epilogue: out = k1*sig(scales)*(f+b2) + k2*y  (rows[] still current)
#pragma unroll
        for (int r = 0; r < 16; ++r) {
            const int row = (r & 3) + ((r >> 2) << 3) + (kh << 2);
            const int g = rows[row];
            if (g >= 0) {
                float res = c1 * (acc2[r] + b2v);
                if (needy) res += k2 * y[(long)g * DIM + n];
                out[(long)g * DIM + n] = res;
            }
        }

        if (!have_next) return;   // uniform across block

        lds_barrier();     // GEMM2 ds-reads + rows[] reads done; stores NOT drained

        // ---- late stage-write: prefetched regs -> LDS (compiler inserts the
        // precise vmcnt wait for v2 here, not at the barriers)
#pragma unroll
        for (int p = 0; p < 4; ++p) {
            const int r = p * 8 + wave;
            if (lane == 0) rows[r] = (r < nrows2) ? g2v[p] : -1;
            const float4 v = v2[p];
            bf16x4 w;
            w[0] = (__bf16)v.x; w[1] = (__bf16)v.y; w[2] = (__bf16)v.z; w[3] = (__bf16)v.w;
            *(bf16x4*)(ab + r * STRIDE + lane * 4) = w;
        }
        lds_barrier();

        ti = ti2; nrows = nrows2;
    }
}

extern "C" void kernel_launch(void* const* d_in, const int* in_sizes, int n_in,
                              void* d_out, int out_size, void* d_ws, size_t ws_size,
                              hipStream_t stream) {
    const float* t      = (const float*)d_in[0];
    const float* y      = (const float*)d_in[1];
    const float* W1     = (const float*)d_in[2];
    const float* b1     = (const float*)d_in[3];
    const float* W2     = (const float*)d_in[4];
    const float* b2     = (const float*)d_in[5];
    const float* scales = (const float*)d_in[6];
    const float* shifta = (const float*)d_in[7];
    const float* shiftb = (const float*)d_in[8];
    float* out = (float*)d_out;

    char* ws = (char*)d_ws;
    int* cursor = (int*)ws;                               // [8]
    int* idxb   = (int*)(ws + 256);                       // [8][32768]
    bf16x8* W1p = (bf16x8*)(ws + 256 + NEXP * BATCH * 4); // packed 1MB
    bf16x8* W2p = W1p + 65536;

    hipMemsetAsync(cursor, 0, 32, stream);
    prep_kernel<<<384, 256, 0, stream>>>(W1, W2, t, W1p, W2p, cursor, idxb);
    // 256 expert-pinned blocks (32 per expert), 1 block/CU
    mlp_kernel<<<256, 512, 0, stream>>>(y, scales, shifta, shiftb, b1, b2,
                                        W1p, W2p, cursor, idxb, out);
}

// Round 7
// 122.606 us; speedup vs baseline: 1.0360x; 1.0360x over previous
//
#include <hip/hip_runtime.h>

#define BATCH 32768
#define DIM   256
#define NEXP  8
#define MT    32          // rows per tile
#define STRIDE 264        // DIM + 8 bf16 pad (measured 0 bank conflicts)

typedef __bf16 bf16x8 __attribute__((ext_vector_type(8)));
typedef __bf16 bf16x4 __attribute__((ext_vector_type(4)));
typedef float  f32x16 __attribute__((ext_vector_type(16)));

static __device__ __forceinline__ float sigmoid_f(float x) {
    return __builtin_amdgcn_rcpf(1.f + __expf(-x));
}
static __device__ __forceinline__ float tanh_f(float x) {
    return 1.f - 2.f * __builtin_amdgcn_rcpf(__expf(2.f * x) + 1.f);
}

// LDS-only barrier (no vmcnt drain): all cross-thread data flows through LDS;
// global loads are consumed by the issuing thread; out is never read back.
static __device__ __forceinline__ void lds_barrier() {
    asm volatile("s_waitcnt lgkmcnt(0)\n\ts_barrier" ::: "memory");
}

// ---- fused prep (unchanged).
// Blocks 0..255: pack W1/W2 fp32->bf16 into MFMA-B-fragment order.
// Layout (bf16x8 units): dst = [e][nt][ks][kh*32+nl], value j = W[e][nt*32+nl][ks*16+kh*8+j]
// Blocks 256..383: scatter sample indices into per-expert regions.
__global__ void prep_kernel(const float* __restrict__ W1, const float* __restrict__ W2,
                            const float* __restrict__ t,
                            bf16x8* __restrict__ W1p, bf16x8* __restrict__ W2p,
                            int* __restrict__ cursor, int* __restrict__ idxb) {
    const int b = blockIdx.x;
    if (b < 256) {
        const int tid = b * 256 + threadIdx.x;   // = e*8192 + col*32 + ks*2 + kh
        const int kh  = tid & 1;
        const int ks  = (tid >> 1) & 15;
        const int col = (tid >> 5) & 255;
        const int e   = tid >> 13;
        const long src = (long)tid * 8;          // consecutive floats -> coalesced
        const float4 a0 = *(const float4*)(W1 + src);
        const float4 a1 = *(const float4*)(W1 + src + 4);
        const float4 c0 = *(const float4*)(W2 + src);
        const float4 c1 = *(const float4*)(W2 + src + 4);
        bf16x8 w1, w2;
        w1[0] = (__bf16)a0.x; w1[1] = (__bf16)a0.y; w1[2] = (__bf16)a0.z; w1[3] = (__bf16)a0.w;
        w1[4] = (__bf16)a1.x; w1[5] = (__bf16)a1.y; w1[6] = (__bf16)a1.z; w1[7] = (__bf16)a1.w;
        w2[0] = (__bf16)c0.x; w2[1] = (__bf16)c0.y; w2[2] = (__bf16)c0.z; w2[3] = (__bf16)c0.w;
        w2[4] = (__bf16)c1.x; w2[5] = (__bf16)c1.y; w2[6] = (__bf16)c1.z; w2[7] = (__bf16)c1.w;
        const int dst = (e << 13) | ((col >> 5) << 10) | (ks << 6) | (kh << 5) | (col & 31);
        W1p[dst] = w1;
        W2p[dst] = w2;
    } else {
        __shared__ int h[NEXP], base[NEXP];
        if (threadIdx.x < NEXP) h[threadIdx.x] = 0;
        __syncthreads();
        const int i = (b - 256) * 256 + threadIdx.x;
        const int e = min((int)(t[i] * 8.0f), NEXP - 1);
        const int lr = atomicAdd(&h[e], 1);
        __syncthreads();
        if (threadIdx.x < NEXP)
            base[threadIdx.x] = atomicAdd(&cursor[threadIdx.x], h[threadIdx.x]);
        __syncthreads();
        idxb[e * BATCH + base[e] + lr] = i;
    }
}

// ---- producer-consumer wave-specialized MLP.
// 256 blocks (1/CU) x 512 threads. Waves 0-3 (G1): hold W1 frags for a
// 64-col slice (128 VGPR), compute GEMM1+tanh -> H. Waves 4-7 (G2): hold
// W2 frags, compute GEMM2+epilogue from H, and stage the NEXT y-tile
// (loads issued early, LDS-written late — no barrier in between). Y and H
// double-buffered, rows 4-deep => every region's activities touch disjoint
// buffers => ONE lds_barrier per tile, and each SIMD runs one G1-wave and
// one G2-wave in DIFFERENT phases (R0/R3/R5/R6 showed same-phase lockstep
// leaves the CU idle on exposed per-phase latency).
__global__ void __launch_bounds__(512, 2)
mlp_kernel(const float* __restrict__ y,
           const float* __restrict__ scales,
           const float* __restrict__ shifta,
           const float* __restrict__ shiftb,
           const float* __restrict__ b1,
           const float* __restrict__ b2,
           const bf16x8* __restrict__ W1p,
           const bf16x8* __restrict__ W2p,
           const int* __restrict__ cnt,
           const int* __restrict__ idxb,
           float* __restrict__ out) {
    __shared__ __bf16 Y[2][MT * STRIDE];   // staged y tiles (bf16)       33.8 KB
    __shared__ __bf16 H[2][MT * STRIDE];   // tanh(h) tiles               33.8 KB
    __shared__ int rowsb[4][MT];           // gathered row indices, 4-deep

    const int tx   = threadIdx.x;
    const int wave = tx >> 6;     // 0..7
    const int lane = tx & 63;
    const int nl   = lane & 31;
    const int kh   = lane >> 5;
    const bool isG1 = (wave < 4);
    const int  w    = wave & 3;        // slice-group 0..3 within role
    const int  n0   = w * 64 + nl;     // output col, slice 0
    const int  n1   = n0 + 32;         // output col, slice 1

    const int e    = blockIdx.x >> 5;   // expert pinned to block
    const int slot = blockIdx.x & 31;
    const int ce   = cnt[e];
    const int nt_e = (ce + MT - 1) >> 5;
    if (slot >= nt_e) return;           // block-uniform
    const int nt   = ((nt_e - slot) + 31) >> 5;   // tiles for this block
    const int* idx_e = idxb + e * BATCH;

    // ---- role-specific weights: 32 frags = 128 VGPR (W1 for G1, W2 for G2)
    const bf16x8* wp = (isG1 ? W1p : W2p) + (e << 13) + ((w * 2) << 10) + lane;
    bf16x8 wf[2][16];
#pragma unroll
    for (int s = 0; s < 2; ++s)
#pragma unroll
        for (int ks = 0; ks < 16; ++ks)
            wf[s][ks] = wp[(s << 10) + (ks << 6)];

    // ---- hoisted constants
    const float sa = sigmoid_f(shifta[0]);
    const float sb = sigmoid_f(shiftb[0]);
    const float k1 = 0.5f * (sb + sa);           // 0.5*(b-a), a=-sa, b=sb
    const float k2 = 0.5f * (sb - sa);           // 0.5*(a+b)
    const bool needy = (k2 != 0.0f);             // exactly 0 with given inputs
    float b1v[2], b2v[2], cc[2];
    b1v[0] = b1[(e << 8) | n0]; b1v[1] = b1[(e << 8) | n1];
    b2v[0] = b2[(e << 8) | n0]; b2v[1] = b2[(e << 8) | n1];
    cc[0]  = k1 * sigmoid_f(scales[n0]); cc[1] = k1 * sigmoid_f(scales[n1]);

    // ---- prologue: G2-waves stage tile 0 into Y[0]/rowsb[0]
    if (!isG1) {
        const int rbase = slot * MT;
        const int nr = min(MT, ce - rbase);
#pragma unroll
        for (int p = 0; p < 8; ++p) {
            const int r  = w * 8 + p;
            const int rr = min(r, nr - 1);
            const int g  = idx_e[rbase + rr];
            if (lane == 0) rowsb[0][r] = (r < nr) ? g : -1;
            const float4 v = *(const float4*)(y + (long)g * DIM + lane * 4);
            bf16x4 wv;
            wv[0] = (__bf16)v.x; wv[1] = (__bf16)v.y; wv[2] = (__bf16)v.z; wv[3] = (__bf16)v.w;
            *(bf16x4*)(&Y[0][r * STRIDE + lane * 4]) = wv;
        }
    }
    lds_barrier();

    // ---- region t: G1 computes tile t (if t<nt); G2 computes tile t-1
    // (if t>=1) and stages tile t+1 (if t+1<nt). Buffers disjoint by parity.
    for (int t = 0; t <= nt; ++t) {
        if (isG1) {
            if (t < nt) {
                const __bf16* ap = &Y[t & 1][nl * STRIDE + kh * 8];
                f32x16 a0v = {}, a1v = {};
#pragma unroll
                for (int ks = 0; ks < 16; ++ks) {
                    bf16x8 a = *(const bf16x8*)(ap + ks * 16);   // 1 read, 2 MFMA
                    a0v = __builtin_amdgcn_mfma_f32_32x32x16_bf16(a, wf[0][ks], a0v, 0, 0, 0);
                    a1v = __builtin_amdgcn_mfma_f32_32x32x16_bf16(a, wf[1][ks], a1v, 0, 0, 0);
                }
                __bf16* hb = &H[t & 1][0];
#pragma unroll
                for (int r = 0; r < 16; ++r) {
                    const int row = (r & 3) + ((r >> 2) << 3) + (kh << 2);
                    hb[row * STRIDE + n0] = (__bf16)tanh_f(a0v[r] + b1v[0]);
                    hb[row * STRIDE + n1] = (__bf16)tanh_f(a1v[r] + b1v[1]);
                }
            }
        } else {
            const bool do_stage = (t + 1 < nt);
            int gs[8]; float4 vs[8]; int nr2 = 0;
            if (do_stage) {   // issue-early: loads ride under GEMM2 below
                const int rbase = (slot + (t + 1) * 32) * MT;
                nr2 = min(MT, ce - rbase);
#pragma unroll
                for (int p = 0; p < 8; ++p) {
                    const int r  = w * 8 + p;
                    const int rr = min(r, nr2 - 1);
                    gs[p] = idx_e[rbase + rr];
                }
#pragma unroll
                for (int p = 0; p < 8; ++p)
                    vs[p] = *(const float4*)(y + (long)gs[p] * DIM + lane * 4);
            }
            if (t >= 1) {
                const __bf16* ap = &H[(t - 1) & 1][nl * STRIDE + kh * 8];
                f32x16 a0v = {}, a1v = {};
#pragma unroll
                for (int ks = 0; ks < 16; ++ks) {
                    bf16x8 a = *(const bf16x8*)(ap + ks * 16);
                    a0v = __builtin_amdgcn_mfma_f32_32x32x16_bf16(a, wf[0][ks], a0v, 0, 0, 0);
                    a1v = __builtin_amdgcn_mfma_f32_32x32x16_bf16(a, wf[1][ks], a1v, 0, 0, 0);
                }
                const int* rb = rowsb[(t - 1) & 3];
#pragma unroll
                for (int r = 0; r < 16; ++r) {
                    const int row = (r & 3) + ((r >> 2) << 3) + (kh << 2);
                    const int g = rb[row];
                    if (g >= 0) {
                        float r0 = cc[0] * (a0v[r] + b2v[0]);
                        float r1 = cc[1] * (a1v[r] + b2v[1]);
                        if (needy) {
                            r0 += k2 * y[(long)g * DIM + n0];
                            r1 += k2 * y[(long)g * DIM + n1];
                        }
                        out[(long)g * DIM + n0] = r0;
                        out[(long)g * DIM + n1] = r1;
                    }
                }
            }
            if (do_stage) {   // write-late: compiler waits vmcnt for vs here
                const int kb = t + 1;
#pragma unroll
                for (int p = 0; p < 8; ++p) {
                    const int r = w * 8 + p;
                    if (lane == 0) rowsb[kb & 3][r] = (r < nr2) ? gs[p] : -1;
                    const float4 v = vs[p];
                    bf16x4 wv;
                    wv[0] = (__bf16)v.x; wv[1] = (__bf16)v.y; wv[2] = (__bf16)v.z; wv[3] = (__bf16)v.w;
                    *(bf16x4*)(&Y[kb & 1][r * STRIDE + lane * 4]) = wv;
                }
            }
        }
        lds_barrier();
    }
}

extern "C" void kernel_launch(void* const* d_in, const int* in_sizes, int n_in,
                              void* d_out, int out_size, void* d_ws, size_t ws_size,
                              hipStream_t stream) {
    const float* t      = (const float*)d_in[0];
    const float* y      = (const float*)d_in[1];
    const float* W1     = (const float*)d_in[2];
    const float* b1     = (const float*)d_in[3];
    const float* W2     = (const float*)d_in[4];
    const float* b2     = (const float*)d_in[5];
    const float* scales = (const float*)d_in[6];
    const float* shifta = (const float*)d_in[7];
    const float* shiftb = (const float*)d_in[8];
    float* out = (float*)d_out;

    char* ws = (char*)d_ws;
    int* cursor = (int*)ws;                               // [8]
    int* idxb   = (int*)(ws + 256);                       // [8][32768]
    bf16x8* W1p = (bf16x8*)(ws + 256 + NEXP * BATCH * 4); // packed 1MB
    bf16x8* W2p = W1p + 65536;

    hipMemsetAsync(cursor, 0, 32, stream);
    prep_kernel<<<384, 256, 0, stream>>>(W1, W2, t, W1p, W2p, cursor, idxb);
    // 256 expert-pinned blocks (32 per expert), 1 block/CU
    mlp_kernel<<<256, 512, 0, stream>>>(y, scales, shifta, shiftb, b1, b2,
                                        W1p, W2p, cursor, idxb, out);
}